// Round 5
// baseline (1746.119 us; speedup 1.0000x reference)
//
#include <hip/hip_runtime.h>
#include <math.h>

namespace {

constexpr int NB  = 64;     // batch
constexpr int NL  = 196;    // L
constexpr int NE  = 2048;   // E
constexpr int ND  = 512;    // D
constexpr int NA  = 512;    // A
constexpr int NM  = 512;    // M
constexpr int NV  = 30000;  // vocab
constexpr int NT  = 21;     // T
constexpr int NML = 20;     // max_len
constexpr int NG  = 4 * ND;                 // 2048 (gates out, col-interleaved j*4+g)
constexpr int KXG = NM + NE + ND;           // 3072 (gates K: [emb | gctx | h])
constexpr int KSPL = 8, KSL = KXG / KSPL;   // 384
// fused h-GEMM N-space: [d (512) | gate (2048) | pred (30000)]
constexpr int NALL = ND + NE + NV;          // 32560
constexpr int OFF_GATE = ND;                // 512
constexpr int OFF_PRED = ND + NE;           // 2560

// ---- workspace layout (float elements) ----
constexpr size_t WS_MEAN = 0;                                  // [64][2048]
constexpr size_t WS_C0   = WS_MEAN + (size_t)NB * NE;
constexpr size_t WS_C1   = WS_C0   + (size_t)NB * ND;
constexpr size_t WS_D    = WS_C1   + (size_t)NB * ND;          // [64][512]
constexpr size_t WS_GATE = WS_D    + (size_t)NB * NA;          // [64][2048] sigmoid applied
constexpr size_t WS_EN   = WS_GATE + (size_t)NB * NE;          // [64][196]
constexpr size_t WS_CNT  = WS_EN   + (size_t)NB * NL;          // 64 ints
constexpr size_t WS_PP   = WS_CNT  + 64;                       // 1048576 (init/gates partials)
constexpr size_t WS_SHB  = WS_PP   + (size_t)1048576;          // short region start
// (short elements from shb)
constexpr size_t SH_HB0  = 0;                                  // [64][512]
constexpr size_t SH_HB1  = SH_HB0  + (size_t)NB * ND;
constexpr size_t SH_XEMB = SH_HB1  + (size_t)NB * ND;          // [20][64][512]
constexpr size_t SH_GCTX = SH_XEMB + (size_t)NML * NB * NM;    // [64][2048]
constexpr size_t SH_EPROJ= SH_GCTX + (size_t)NB * NE;          // [12544][512]
constexpr size_t SH_WET  = SH_EPROJ+ (size_t)NB * NL * NA;     // [512][2048]
constexpr size_t SH_WIHX = SH_WET  + (size_t)NA * NE;          // [2048][3072] col-perm
constexpr size_t SH_WALL = SH_WIHX + (size_t)NG * KXG;         // [32560][512]
constexpr size_t SH_ENCBF= SH_WALL + (size_t)NALL * ND;        // [64][196][2048] optional
constexpr size_t SH_END  = SH_ENCBF+ (size_t)NB * NL * NE;
constexpr size_t BYTES_ENC = WS_SHB * 4 + SH_END * 2;

typedef __attribute__((ext_vector_type(8))) short short8v;
typedef __attribute__((ext_vector_type(4))) float f32x4;

__device__ __forceinline__ float sigmoidf_(float x) { return 1.f / (1.f + expf(-x)); }
__device__ __forceinline__ short f2bf(float f) {
  unsigned u = __float_as_uint(f);
  return (short)((u + 0x7FFFu + ((u >> 16) & 1u)) >> 16);
}
__device__ __forceinline__ float bf2f(short s) {
  return __uint_as_float(((unsigned)(unsigned short)s) << 16);
}

// ---------- MFMA building blocks ----------
// LDS tile: [row][64 k] bf16, 8 x 16B chunks/row, chunk for global kb sits at
// slot kb ^ (row&7). Staged via global_load_lds with PRE-SWIZZLED global source
// (linear LDS dest = wave-uniform base + lane*16B; 8 rows per wave-issue).

__device__ __forceinline__ void gload16(const short* g, short* l) {
  __builtin_amdgcn_global_load_lds(
      (const __attribute__((address_space(1))) unsigned int*)(g),
      (__attribute__((address_space(3))) unsigned int*)(l), 16, 0, 0);
}

template <int R>  // stage R rows x 64 k bf16 (R multiple of 8); 4 waves assumed
__device__ __forceinline__ void stage_direct(const short* __restrict__ src, int ldK,
                                             int rowClamp, short* lds, int tid) {
  int wv = tid >> 6, lane = tid & 63;
  int sub = lane >> 3;             // dest row within 8-row group
  int kb  = (lane & 7) ^ sub;      // pre-swizzled source chunk
#pragma unroll
  for (int g = wv; g < R / 8; g += 4) {
    int row = g * 8 + sub;
    int r = row < rowClamp ? row : rowClamp;
    gload16(src + (size_t)r * ldK + (kb << 3), lds + g * 512);
  }
}

template <int R>  // reg-staged f32->bf16 fallback (writes swizzled slots directly)
__device__ __forceinline__ void stage_f32cvt(const float* __restrict__ src, int ldK,
                                             short* lds, int tid) {
#pragma unroll
  for (int cidx = tid; cidx < R * 8; cidx += 256) {
    int row = cidx >> 3, kb = cidx & 7;
    const float* p = src + (size_t)row * ldK + kb * 8;
    float4 x = *(const float4*)p;
    float4 y = *(const float4*)(p + 4);
    short8v s;
    s[0] = f2bf(x.x); s[1] = f2bf(x.y); s[2] = f2bf(x.z); s[3] = f2bf(x.w);
    s[4] = f2bf(y.x); s[5] = f2bf(y.y); s[6] = f2bf(y.z); s[7] = f2bf(y.w);
    *(short8v*)(lds + row * 64 + ((kb ^ (row & 7)) << 3)) = s;
  }
}

template <int FM, int FN>
__device__ __forceinline__ void mma_tiles(const short* ldsA, const short* ldsB,
                                          int wr, int wc, int lane, f32x4 acc[FM][FN]) {
  int l15 = lane & 15;
#pragma unroll
  for (int kk = 0; kk < 2; ++kk) {
    int kb0 = kk * 4 + (lane >> 4);
    short8v a[FM], b[FN];
#pragma unroll
    for (int m = 0; m < FM; ++m) {
      int row = wr * FM * 16 + m * 16 + l15;
      a[m] = *(const short8v*)(ldsA + row * 64 + ((kb0 ^ (row & 7)) << 3));
    }
#pragma unroll
    for (int n = 0; n < FN; ++n) {
      int row = wc * FN * 16 + n * 16 + l15;
      b[n] = *(const short8v*)(ldsB + row * 64 + ((kb0 ^ (row & 7)) << 3));
    }
#pragma unroll
    for (int m = 0; m < FM; ++m)
#pragma unroll
      for (int n = 0; n < FN; ++n)
        acc[m][n] = __builtin_amdgcn_mfma_f32_16x16x32_bf16(a[m], b[n], acc[m][n], 0, 0, 0);
  }
}

// ---------- one-time kernels ----------

// transpose+convert; PERM interleaves gate columns: n' = (n&511)*4 + (n>>9)
template <bool PERM>
__global__ __launch_bounds__(256) void k_tcvt(const float* __restrict__ src, int Ks, int Ns,
                                              short* __restrict__ dst, int ldDst, int kOff) {
  __shared__ float tbuf[32][33];
  int n0 = blockIdx.x * 32, k0 = blockIdx.y * 32;
  int tx = threadIdx.x, ty = threadIdx.y;  // 32 x 8
#pragma unroll
  for (int i = 0; i < 32; i += 8) {
    int k = k0 + ty + i, n = n0 + tx;
    tbuf[ty + i][tx] = (k < Ks && n < Ns) ? src[(size_t)k * Ns + n] : 0.f;
  }
  __syncthreads();
#pragma unroll
  for (int i = 0; i < 32; i += 8) {
    int n = n0 + ty + i, k = k0 + tx;
    if (n < Ns && k < Ks) {
      int nd = PERM ? (((n & 511) << 2) | (n >> 9)) : n;
      dst[(size_t)nd * ldDst + kOff + k] = f2bf(tbuf[tx][ty + i]);
    }
  }
}

__global__ void k_zero(int* __restrict__ cnt) {
  if (threadIdx.x < 32) cnt[threadIdx.x] = 0;
}

// fused: encbf (optional) + column mean, single pass over enc. grid (8, 64)
template <bool BF>
__global__ __launch_bounds__(256) void k_prep(const float* __restrict__ enc,
                                              short* __restrict__ encbf,
                                              float* __restrict__ mean_enc) {
  int b = blockIdx.y;
  int e = blockIdx.x * 256 + threadIdx.x;
  const float* p = enc + (size_t)b * NL * NE + e;
  short* q = encbf + (size_t)b * NL * NE + e;
  float s = 0.f;
  for (int l = 0; l < NL; ++l) {
    float v = p[(size_t)l * NE];
    s += v;
    if (BF) q[(size_t)l * NE] = f2bf(v);
  }
  mean_enc[(size_t)b * NE + e] = s * (1.f / NL);
}

__global__ void k_xemb(const int* __restrict__ caps, const float* __restrict__ emb,
                       short* __restrict__ xemb) {
  int i = blockIdx.x * 256 + threadIdx.x;
  int m = i & (NM - 1), b = (i >> 9) & (NB - 1), t = i >> 15;
  xemb[i] = f2bf(emb[(size_t)caps[b * NT + t] * NM + m]);
}

// h0/c0 partials: 16-way K-split. grid (256, 16)
__global__ void k_init0(const float* __restrict__ mean_enc, const float* __restrict__ W_h0,
                        const float* __restrict__ W_c0, float* __restrict__ PP) {
  int idx = blockIdx.x * 256 + threadIdx.x;  // b*1024 + half*512 + j
  int ks = blockIdx.y;
  int b = idx >> 10, jh = idx & 1023, half = jh >> 9, j = jh & 511;
  const float* W = half ? W_c0 : W_h0;
  const float* mp = mean_enc + (size_t)b * NE + ks * 128;
  const float* Wp = W + (size_t)(ks * 128) * ND + j;
  float acc = 0.f;
#pragma unroll 4
  for (int k = 0; k < 128; ++k) acc = fmaf(mp[k], Wp[(size_t)k * ND], acc);
  PP[(size_t)ks * 65536 + idx] = acc;
}

__global__ void k_init1(const float* __restrict__ PP, const float* __restrict__ b_h0,
                        const float* __restrict__ b_c0, float* __restrict__ c0,
                        short* __restrict__ hb0) {
  int idx = blockIdx.x * 256 + threadIdx.x;  // b*512 + j
  int b = idx >> 9, j = idx & 511;
  float ah = b_h0[j], ac = b_c0[j];
  for (int s = 0; s < 16; ++s) {
    const float* p = PP + (size_t)s * 65536 + b * 1024;
    ah += p[j]; ac += p[512 + j];
  }
  c0[idx] = tanhf(ac);
  hb0[idx] = f2bf(tanhf(ah));
}

// e_proj = enc @ W_enc + b_enc (bf16 out). 128x128 tile, 1D grid 392, XCD-chunked
template <bool BF>
__global__ __launch_bounds__(256) void k_eproj(const float* __restrict__ enc,
                                               const short* __restrict__ encbf,
                                               const short* __restrict__ We_t,
                                               const float* __restrict__ b_enc,
                                               short* __restrict__ e_proj) {
  constexpr int FM = 4, FN = 4;  // 128 x 128
  __shared__ short ldsA[128 * 64], ldsB[128 * 64];
  // logical id: contiguous per XCD (p%8 = XCD under round-robin dispatch)
  int p = blockIdx.x;
  int l = (p & 7) * 49 + (p >> 3);       // 392 = 8*49
  int bn = (l & 3) * 128, bm = (l >> 2) * 128;
  int tid = threadIdx.x, lane = tid & 63, wave = tid >> 6, wr = wave >> 1, wc = wave & 1;
  f32x4 acc[FM][FN];
#pragma unroll
  for (int m = 0; m < FM; ++m)
#pragma unroll
    for (int n = 0; n < FN; ++n) acc[m][n] = (f32x4){0.f, 0.f, 0.f, 0.f};
  for (int k0 = 0; k0 < NE; k0 += 64) {
    __syncthreads();
    if (BF) stage_direct<128>(encbf + (size_t)bm * NE + k0, NE, 127, ldsA, tid);
    else    stage_f32cvt<128>(enc + (size_t)bm * NE + k0, NE, ldsA, tid);
    stage_direct<128>(We_t + (size_t)bn * NE + k0, NE, 127, ldsB, tid);
    __syncthreads();
    mma_tiles<FM, FN>(ldsA, ldsB, wr, wc, lane, acc);
  }
#pragma unroll
  for (int m = 0; m < FM; ++m)
#pragma unroll
    for (int n = 0; n < FN; ++n) {
      int col = bn + wc * FN * 16 + n * 16 + (lane & 15);
      float bias = b_enc[col];
#pragma unroll
      for (int r = 0; r < 4; ++r) {
        int row = bm + wr * FM * 16 + m * 16 + (lane >> 4) * 4 + r;
        e_proj[(size_t)row * NA + col] = f2bf(acc[m][n][r] + bias);
      }
    }
}

// fused h-GEMM: h_bf [64,512] @ Wall_t^T -> d | gate | preds(t). 64x64 tile
__global__ __launch_bounds__(256) void k_hgemm(const short* __restrict__ h_bf,
                                               const short* __restrict__ Wall_t,
                                               const float* __restrict__ b_dec,
                                               const float* __restrict__ b_beta,
                                               const float* __restrict__ b_fc,
                                               const int* __restrict__ clen,
                                               float* __restrict__ d_buf,
                                               float* __restrict__ gatebuf,
                                               float* __restrict__ preds, int t) {
  constexpr int FM = 2, FN = 2;  // 64 x 64, 4 waves
  __shared__ short ldsA[64 * 64], ldsB[64 * 64];
  int bn = blockIdx.x * 64;
  int tid = threadIdx.x, lane = tid & 63, wave = tid >> 6, wr = wave >> 1, wc = wave & 1;
  int rowClampB = NALL - 1 - bn; if (rowClampB > 63) rowClampB = 63;
  f32x4 acc[FM][FN];
#pragma unroll
  for (int m = 0; m < FM; ++m)
#pragma unroll
    for (int n = 0; n < FN; ++n) acc[m][n] = (f32x4){0.f, 0.f, 0.f, 0.f};
  for (int k0 = 0; k0 < ND; k0 += 64) {
    __syncthreads();
    stage_direct<64>(h_bf + k0, ND, 63, ldsA, tid);
    stage_direct<64>(Wall_t + (size_t)bn * ND + k0, ND, rowClampB, ldsB, tid);
    __syncthreads();
    mma_tiles<FM, FN>(ldsA, ldsB, wr, wc, lane, acc);
  }
#pragma unroll
  for (int m = 0; m < FM; ++m)
#pragma unroll
    for (int r = 0; r < 4; ++r) {
      int row = wr * FM * 16 + m * 16 + (lane >> 4) * 4 + r;  // batch
      float mf = ((clen[row] - 1) > t) ? 1.f : 0.f;
#pragma unroll
      for (int n = 0; n < FN; ++n) {
        int col = bn + wc * FN * 16 + n * 16 + (lane & 15);
        float a = acc[m][n][r];
        if (bn < OFF_GATE) {
          d_buf[(size_t)row * NA + col] = a + b_dec[col];
        } else if (bn < OFF_PRED) {
          int e = col - OFF_GATE;
          gatebuf[(size_t)row * NE + e] = sigmoidf_(a + b_beta[e]);
        } else {
          int v = col - OFF_PRED;
          if (v < NV) preds[((size_t)row * NML + t) * NV + v] = mf * (a + b_fc[v]);
        }
      }
    }
}

// ---------- per-step kernels ----------

__global__ __launch_bounds__(256) void k_energy(const short* __restrict__ e_proj,
                                                const float* __restrict__ d_buf,
                                                const float* __restrict__ w_att,
                                                const float* __restrict__ b_att,
                                                float* __restrict__ energy) {
  int tid = threadIdx.x, wave = tid >> 6, lane = tid & 63;
  int row = blockIdx.x * 4 + wave;  // b*196 + l
  int b = row / NL;
  short8v ev = *(const short8v*)(e_proj + (size_t)row * NA + lane * 8);
  const float* dp = d_buf + (size_t)b * NA + lane * 8;
  float4 d0 = *(const float4*)dp, d1 = *(const float4*)(dp + 4);
  const float* wp = w_att + lane * 8;
  float4 w0 = *(const float4*)wp, w1 = *(const float4*)(wp + 4);
  float dd[8] = {d0.x, d0.y, d0.z, d0.w, d1.x, d1.y, d1.z, d1.w};
  float ww[8] = {w0.x, w0.y, w0.z, w0.w, w1.x, w1.y, w1.z, w1.w};
  float acc = 0.f;
#pragma unroll
  for (int i = 0; i < 8; ++i) {
    float v = bf2f(ev[i]) + dd[i];
    acc = fmaf(fmaxf(v, 0.f), ww[i], acc);
  }
#pragma unroll
  for (int off = 32; off; off >>= 1) acc += __shfl_down(acc, off);
  if (lane == 0) energy[row] = acc + b_att[0];
}

// softmax (per-block recompute) + ctx + gate -> gctx bf16. grid (4, 64)
template <bool BF>
__global__ __launch_bounds__(256) void k_ctx(const short* __restrict__ encbf,
                                             const float* __restrict__ encf,
                                             const float* __restrict__ energy,
                                             const float* __restrict__ gatebuf,
                                             const int* __restrict__ clen,
                                             short* __restrict__ gctx,
                                             float* __restrict__ alphas_out, int t) {
  int b = blockIdx.y, e0 = blockIdx.x * 512, tid = threadIdx.x;
  __shared__ float al[NL];
  __shared__ float red[8];
  int wave = tid >> 6, lane = tid & 63;
  float v = (tid < NL) ? energy[b * NL + tid] : -INFINITY;
  float mx = v;
#pragma unroll
  for (int off = 32; off; off >>= 1) mx = fmaxf(mx, __shfl_down(mx, off));
  if (lane == 0) red[wave] = mx;
  __syncthreads();
  if (tid == 0) red[0] = fmaxf(fmaxf(red[0], red[1]), fmaxf(red[2], red[3]));
  __syncthreads();
  mx = red[0];
  float ex = (tid < NL) ? expf(v - mx) : 0.f;
  float sm = ex;
#pragma unroll
  for (int off = 32; off; off >>= 1) sm += __shfl_down(sm, off);
  if (lane == 0) red[4 + wave] = sm;
  __syncthreads();
  if (tid == 0) red[0] = 1.f / (red[4] + red[5] + red[6] + red[7]);
  __syncthreads();
  float alv = ex * red[0];
  if (tid < NL) {
    al[tid] = alv;
    if (blockIdx.x == 0) {
      float mf = ((clen[b] - 1) > t) ? 1.f : 0.f;
      alphas_out[((size_t)b * NML + t) * NL + tid] = alv * mf;
    }
  }
  __syncthreads();
  float cx0 = 0.f, cx1 = 0.f;
  if (BF) {
    const unsigned* p = (const unsigned*)(encbf + (size_t)b * NL * NE + e0) + tid;
#pragma unroll 4
    for (int l = 0; l < NL; ++l) {
      unsigned u = p[(size_t)l * (NE / 2)];
      cx0 = fmaf(al[l], bf2f((short)(u & 0xffffu)), cx0);
      cx1 = fmaf(al[l], bf2f((short)(u >> 16)), cx1);
    }
  } else {
    const float* p = encf + (size_t)b * NL * NE + e0 + 2 * tid;
#pragma unroll 4
    for (int l = 0; l < NL; ++l) {
      float2 u = *(const float2*)(p + (size_t)l * NE);
      cx0 = fmaf(al[l], u.x, cx0);
      cx1 = fmaf(al[l], u.y, cx1);
    }
  }
  int e = e0 + 2 * tid;
  const float* gp = gatebuf + (size_t)b * NE + e;
  unsigned out = (unsigned)(unsigned short)f2bf(cx0 * gp[0]) |
                 ((unsigned)(unsigned short)f2bf(cx1 * gp[1]) << 16);
  *(unsigned*)(gctx + (size_t)b * NE + e) = out;
}

// gates GEMM [emb|gctx|h] @ Wihx_t^T (col-interleaved) + fused LSTM tail.
// grid (32, 8). Last-arriving ks-block per bn reduces P and does pointwise.
__global__ __launch_bounds__(256) void k_gates(const short* __restrict__ xemb_t,
                                               const short* __restrict__ gctx,
                                               const short* __restrict__ h_prev,
                                               const short* __restrict__ Wihx_t,
                                               float* __restrict__ P,
                                               int* __restrict__ cnt,
                                               const float* __restrict__ b_ih,
                                               const float* __restrict__ b_hh,
                                               const float* __restrict__ c_prev,
                                               float* __restrict__ c_next,
                                               short* __restrict__ h_next) {
  constexpr int FM = 2, FN = 2;  // 64 x 64
  __shared__ short ldsA[64 * 64], ldsB[64 * 64];
  __shared__ int isLast;
  int bnb = blockIdx.x, bn = bnb * 64, ks = blockIdx.y;
  int tid = threadIdx.x, lane = tid & 63, wave = tid >> 6, wr = wave >> 1, wc = wave & 1;
  f32x4 acc[FM][FN];
#pragma unroll
  for (int m = 0; m < FM; ++m)
#pragma unroll
    for (int n = 0; n < FN; ++n) acc[m][n] = (f32x4){0.f, 0.f, 0.f, 0.f};
  int kend = (ks + 1) * KSL;
  for (int k0 = ks * KSL; k0 < kend; k0 += 64) {
    const short* asrc; int aldk;
    if (k0 < NM)           { asrc = xemb_t + k0;              aldk = NM; }
    else if (k0 < NM + NE) { asrc = gctx + (k0 - NM);         aldk = NE; }
    else                   { asrc = h_prev + (k0 - NM - NE);  aldk = ND; }
    __syncthreads();
    stage_direct<64>(asrc, aldk, 63, ldsA, tid);
    stage_direct<64>(Wihx_t + (size_t)bn * KXG + k0, KXG, 63, ldsB, tid);
    __syncthreads();
    mma_tiles<FM, FN>(ldsA, ldsB, wr, wc, lane, acc);
  }
#pragma unroll
  for (int m = 0; m < FM; ++m)
#pragma unroll
    for (int n = 0; n < FN; ++n) {
      int col = bn + wc * FN * 16 + n * 16 + (lane & 15);
#pragma unroll
      for (int r = 0; r < 4; ++r) {
        int row = wr * FM * 16 + m * 16 + (lane >> 4) * 4 + r;
        P[((size_t)ks * NB + row) * NG + col] = acc[m][n][r];
      }
    }
  // ---- last-block LSTM tail ----
  __threadfence();
  __syncthreads();
  if (tid == 0) isLast = (atomicAdd(&cnt[bnb], 1) == KSPL - 1);
  __syncthreads();
  if (!isLast) return;
  __threadfence();
  for (int pr = tid; pr < NB * 16; pr += 256) {
    int b = pr >> 4, jj = pr & 15;
    int j = bnb * 16 + jj;
    float gi = 0.f, gf = 0.f, gg = 0.f, go = 0.f;
#pragma unroll
    for (int s = 0; s < KSPL; ++s) {
      float4 v = *(const float4*)&P[((size_t)s * NB + b) * NG + bn + jj * 4];
      gi += v.x; gf += v.y; gg += v.z; go += v.w;
    }
    gi += b_ih[j] + b_hh[j];
    gf += b_ih[j + ND] + b_hh[j + ND];
    gg += b_ih[j + 2 * ND] + b_hh[j + 2 * ND];
    go += b_ih[j + 3 * ND] + b_hh[j + 3 * ND];
    float cn = sigmoidf_(gf) * c_prev[b * ND + j] + sigmoidf_(gi) * tanhf(gg);
    float hn = sigmoidf_(go) * tanhf(cn);
    c_next[b * ND + j] = cn;
    h_next[b * ND + j] = f2bf(hn);
  }
  if (tid == 0) cnt[bnb] = 0;  // re-arm for next step (kernel boundary orders this)
}

}  // namespace

extern "C" void kernel_launch(void* const* d_in, const int* in_sizes, int n_in,
                              void* d_out, int out_size, void* d_ws, size_t ws_size,
                              hipStream_t stream) {
  (void)in_sizes; (void)n_in; (void)out_size;
  const float* enc    = (const float*)d_in[0];
  const int*   caps   = (const int*)d_in[1];
  const int*   clen   = (const int*)d_in[2];
  const float* W_enc  = (const float*)d_in[3];
  const float* b_enc  = (const float*)d_in[4];
  const float* W_dec  = (const float*)d_in[5];
  const float* b_dec  = (const float*)d_in[6];
  const float* w_att  = (const float*)d_in[7];
  const float* b_att  = (const float*)d_in[8];
  const float* emb    = (const float*)d_in[9];
  const float* W_ih   = (const float*)d_in[10];
  const float* b_ih   = (const float*)d_in[11];
  const float* W_hh   = (const float*)d_in[12];
  const float* b_hh   = (const float*)d_in[13];
  const float* W_h0   = (const float*)d_in[14];
  const float* b_h0   = (const float*)d_in[15];
  const float* W_c0   = (const float*)d_in[16];
  const float* b_c0   = (const float*)d_in[17];
  const float* W_beta = (const float*)d_in[18];
  const float* b_beta = (const float*)d_in[19];
  const float* W_fc   = (const float*)d_in[20];
  const float* b_fc   = (const float*)d_in[21];

  float* ws     = (float*)d_ws;
  float* preds  = (float*)d_out;                   // [B][ML][V]
  float* alphas = preds + (size_t)NB * NML * NV;   // [B][ML][L]

  float* mean_enc = ws + WS_MEAN;
  float* cbuf[2]  = {ws + WS_C0, ws + WS_C1};
  float* d_buf    = ws + WS_D;
  float* gatebuf  = ws + WS_GATE;
  float* energy   = ws + WS_EN;
  int*   cnt      = (int*)(ws + WS_CNT);
  float* PP       = ws + WS_PP;
  short* shb      = (short*)(ws + WS_SHB);
  short* hbuf[2]  = {shb + SH_HB0, shb + SH_HB1};
  short* xemb     = shb + SH_XEMB;
  short* gctx     = shb + SH_GCTX;
  short* e_proj   = shb + SH_EPROJ;
  short* We_t     = shb + SH_WET;
  short* Wihx_t   = shb + SH_WIHX;
  short* Wall_t   = shb + SH_WALL;
  short* encbf    = shb + SH_ENCBF;
  const bool use_bf = ws_size >= BYTES_ENC;

  // one-time weight transposes (dst[n][k] bf16)
  k_tcvt<false><<<dim3(NA / 32, NE / 32), dim3(32, 8), 0, stream>>>(W_enc, NE, NA, We_t, NE, 0);
  k_tcvt<true><<<dim3(NG / 32, (NM + NE) / 32), dim3(32, 8), 0, stream>>>(
      W_ih, NM + NE, NG, Wihx_t, KXG, 0);
  k_tcvt<true><<<dim3(NG / 32, ND / 32), dim3(32, 8), 0, stream>>>(
      W_hh, ND, NG, Wihx_t, KXG, NM + NE);
  k_tcvt<false><<<dim3(NA / 32, ND / 32), dim3(32, 8), 0, stream>>>(W_dec, ND, NA, Wall_t, ND, 0);
  k_tcvt<false><<<dim3(NE / 32, ND / 32), dim3(32, 8), 0, stream>>>(
      W_beta, ND, NE, Wall_t + (size_t)OFF_GATE * ND, ND, 0);
  k_tcvt<false><<<dim3((NV + 31) / 32, ND / 32), dim3(32, 8), 0, stream>>>(
      W_fc, ND, NV, Wall_t + (size_t)OFF_PRED * ND, ND, 0);
  k_zero<<<1, 64, 0, stream>>>(cnt);
  if (use_bf)
    k_prep<true><<<dim3(NE / 256, NB), 256, 0, stream>>>(enc, encbf, mean_enc);
  else
    k_prep<false><<<dim3(NE / 256, NB), 256, 0, stream>>>(enc, encbf, mean_enc);
  k_xemb<<<(NML * NB * NM) / 256, 256, 0, stream>>>(caps, emb, xemb);

  k_init0<<<dim3(256, 16), 256, 0, stream>>>(mean_enc, W_h0, W_c0, PP);
  k_init1<<<(NB * ND) / 256, 256, 0, stream>>>(PP, b_h0, b_c0, cbuf[0], hbuf[0]);
  if (use_bf)
    k_eproj<true><<<392, 256, 0, stream>>>(enc, encbf, We_t, b_enc, e_proj);
  else
    k_eproj<false><<<392, 256, 0, stream>>>(enc, encbf, We_t, b_enc, e_proj);
  // h0-dependent d + gate only (first 40 column-tiles)
  k_hgemm<<<OFF_PRED / 64, 256, 0, stream>>>(hbuf[0], Wall_t, b_dec, b_beta, b_fc, clen,
                                             d_buf, gatebuf, preds, 0);

  for (int t = 0; t < NML; ++t) {
    short* h_prev = hbuf[t & 1];
    short* h_next = hbuf[1 - (t & 1)];
    float* c_prev = cbuf[t & 1];
    float* c_next = cbuf[1 - (t & 1)];
    k_energy<<<(NB * NL) / 4, 256, 0, stream>>>(e_proj, d_buf, w_att, b_att, energy);
    if (use_bf)
      k_ctx<true><<<dim3(NE / 512, NB), 256, 0, stream>>>(encbf, enc, energy, gatebuf,
                                                          clen, gctx, alphas, t);
    else
      k_ctx<false><<<dim3(NE / 512, NB), 256, 0, stream>>>(encbf, enc, energy, gatebuf,
                                                           clen, gctx, alphas, t);
    k_gates<<<dim3(NG / 64, KSPL), 256, 0, stream>>>(xemb + (size_t)t * NB * NM, gctx,
                                                     h_prev, Wihx_t, PP, cnt, b_ih, b_hh,
                                                     c_prev, c_next, h_next);
    // preds(t) + d/gate for step t+1
    k_hgemm<<<(NALL + 63) / 64, 256, 0, stream>>>(h_next, Wall_t, b_dec, b_beta, b_fc,
                                                  clen, d_buf, gatebuf, preds, t);
  }
}

// Round 6
// 1156.637 us; speedup vs baseline: 1.5097x; 1.5097x over previous
//
#include <hip/hip_runtime.h>
#include <math.h>

namespace {

constexpr int NB  = 64;     // batch
constexpr int NL  = 196;    // L
constexpr int NE  = 2048;   // E
constexpr int ND  = 512;    // D
constexpr int NA  = 512;    // A
constexpr int NM  = 512;    // M
constexpr int NV  = 30000;  // vocab
constexpr int NT  = 21;     // T
constexpr int NML = 20;     // max_len
constexpr int NG  = 4 * ND;                 // 2048 (gates out, col-interleaved j*4+g)
constexpr int KXG = NM + NE + ND;           // 3072 (gates K: [emb | gctx | h])
constexpr int KSPL = 8, KSL = KXG / KSPL;   // 384
// fused h-GEMM N-space: [d (512) | gate (2048) | pred (30000)]
constexpr int NALL = ND + NE + NV;          // 32560
constexpr int OFF_GATE = ND;                // 512
constexpr int OFF_PRED = ND + NE;           // 2560

// ---- workspace layout (float elements) ----
constexpr size_t WS_MEAN = 0;                                  // [64][2048]
constexpr size_t WS_C0   = WS_MEAN + (size_t)NB * NE;
constexpr size_t WS_C1   = WS_C0   + (size_t)NB * ND;
constexpr size_t WS_D    = WS_C1   + (size_t)NB * ND;          // [64][512]
constexpr size_t WS_GATE = WS_D    + (size_t)NB * NA;          // [64][2048] sigmoid applied
constexpr size_t WS_EN   = WS_GATE + (size_t)NB * NE;          // [64][196]
constexpr size_t WS_CNT  = WS_EN   + (size_t)NB * NL;          // (unused, layout keep)
constexpr size_t WS_PP   = WS_CNT  + 64;                       // 1048576 (init/gates partials)
constexpr size_t WS_SHB  = WS_PP   + (size_t)1048576;          // short region start
// (short elements from shb)
constexpr size_t SH_HB0  = 0;                                  // [64][512]
constexpr size_t SH_HB1  = SH_HB0  + (size_t)NB * ND;
constexpr size_t SH_XEMB = SH_HB1  + (size_t)NB * ND;          // [20][64][512]
constexpr size_t SH_GCTX = SH_XEMB + (size_t)NML * NB * NM;    // [64][2048]
constexpr size_t SH_EPROJ= SH_GCTX + (size_t)NB * NE;          // [12544][512]
constexpr size_t SH_WET  = SH_EPROJ+ (size_t)NB * NL * NA;     // [512][2048]
constexpr size_t SH_WIHX = SH_WET  + (size_t)NA * NE;          // [2048][3072] col-perm
constexpr size_t SH_WALL = SH_WIHX + (size_t)NG * KXG;         // [32560][512]
constexpr size_t SH_ENCBF= SH_WALL + (size_t)NALL * ND;        // [64][196][2048] optional
constexpr size_t SH_END  = SH_ENCBF+ (size_t)NB * NL * NE;
constexpr size_t BYTES_ENC = WS_SHB * 4 + SH_END * 2;

typedef __attribute__((ext_vector_type(8))) short short8v;
typedef __attribute__((ext_vector_type(4))) float f32x4;

__device__ __forceinline__ float sigmoidf_(float x) { return 1.f / (1.f + expf(-x)); }
__device__ __forceinline__ short f2bf(float f) {
  unsigned u = __float_as_uint(f);
  return (short)((u + 0x7FFFu + ((u >> 16) & 1u)) >> 16);
}
__device__ __forceinline__ float bf2f(short s) {
  return __uint_as_float(((unsigned)(unsigned short)s) << 16);
}

// ---------- MFMA building blocks ----------
// LDS tile: [row][64 k] bf16, 8 x 16B chunks/row, chunk for global kb sits at
// slot kb ^ (row&7). Staged via global_load_lds with PRE-SWIZZLED global source
// (linear LDS dest = wave-uniform base + lane*16B; 8 rows per wave-issue).

__device__ __forceinline__ void gload16(const short* g, short* l) {
  __builtin_amdgcn_global_load_lds(
      (const __attribute__((address_space(1))) unsigned int*)(g),
      (__attribute__((address_space(3))) unsigned int*)(l), 16, 0, 0);
}

template <int R>  // stage R rows x 64 k bf16 (R multiple of 8); 4 waves assumed
__device__ __forceinline__ void stage_direct(const short* __restrict__ src, int ldK,
                                             int rowClamp, short* lds, int tid) {
  int wv = tid >> 6, lane = tid & 63;
  int sub = lane >> 3;             // dest row within 8-row group
  int kb  = (lane & 7) ^ sub;      // pre-swizzled source chunk
#pragma unroll
  for (int g = wv; g < R / 8; g += 4) {
    int row = g * 8 + sub;
    int r = row < rowClamp ? row : rowClamp;
    gload16(src + (size_t)r * ldK + (kb << 3), lds + g * 512);
  }
}

template <int R>  // reg-staged f32->bf16 fallback (writes swizzled slots directly)
__device__ __forceinline__ void stage_f32cvt(const float* __restrict__ src, int ldK,
                                             short* lds, int tid) {
#pragma unroll
  for (int cidx = tid; cidx < R * 8; cidx += 256) {
    int row = cidx >> 3, kb = cidx & 7;
    const float* p = src + (size_t)row * ldK + kb * 8;
    float4 x = *(const float4*)p;
    float4 y = *(const float4*)(p + 4);
    short8v s;
    s[0] = f2bf(x.x); s[1] = f2bf(x.y); s[2] = f2bf(x.z); s[3] = f2bf(x.w);
    s[4] = f2bf(y.x); s[5] = f2bf(y.y); s[6] = f2bf(y.z); s[7] = f2bf(y.w);
    *(short8v*)(lds + row * 64 + ((kb ^ (row & 7)) << 3)) = s;
  }
}

template <int FM, int FN>
__device__ __forceinline__ void mma_tiles(const short* ldsA, const short* ldsB,
                                          int wr, int wc, int lane, f32x4 acc[FM][FN]) {
  int l15 = lane & 15;
#pragma unroll
  for (int kk = 0; kk < 2; ++kk) {
    int kb0 = kk * 4 + (lane >> 4);
    short8v a[FM], b[FN];
#pragma unroll
    for (int m = 0; m < FM; ++m) {
      int row = wr * FM * 16 + m * 16 + l15;
      a[m] = *(const short8v*)(ldsA + row * 64 + ((kb0 ^ (row & 7)) << 3));
    }
#pragma unroll
    for (int n = 0; n < FN; ++n) {
      int row = wc * FN * 16 + n * 16 + l15;
      b[n] = *(const short8v*)(ldsB + row * 64 + ((kb0 ^ (row & 7)) << 3));
    }
#pragma unroll
    for (int m = 0; m < FM; ++m)
#pragma unroll
      for (int n = 0; n < FN; ++n)
        acc[m][n] = __builtin_amdgcn_mfma_f32_16x16x32_bf16(a[m], b[n], acc[m][n], 0, 0, 0);
  }
}

// ---------- one-time kernels ----------

// transpose+convert; PERM interleaves gate columns: n' = (n&511)*4 + (n>>9)
template <bool PERM>
__global__ __launch_bounds__(256) void k_tcvt(const float* __restrict__ src, int Ks, int Ns,
                                              short* __restrict__ dst, int ldDst, int kOff) {
  __shared__ float tbuf[32][33];
  int n0 = blockIdx.x * 32, k0 = blockIdx.y * 32;
  int tx = threadIdx.x, ty = threadIdx.y;  // 32 x 8
#pragma unroll
  for (int i = 0; i < 32; i += 8) {
    int k = k0 + ty + i, n = n0 + tx;
    tbuf[ty + i][tx] = (k < Ks && n < Ns) ? src[(size_t)k * Ns + n] : 0.f;
  }
  __syncthreads();
#pragma unroll
  for (int i = 0; i < 32; i += 8) {
    int n = n0 + ty + i, k = k0 + tx;
    if (n < Ns && k < Ks) {
      int nd = PERM ? (((n & 511) << 2) | (n >> 9)) : n;
      dst[(size_t)nd * ldDst + kOff + k] = f2bf(tbuf[tx][ty + i]);
    }
  }
}

// fused: encbf (optional) + column mean, single pass over enc. grid (8, 64)
template <bool BF>
__global__ __launch_bounds__(256) void k_prep(const float* __restrict__ enc,
                                              short* __restrict__ encbf,
                                              float* __restrict__ mean_enc) {
  int b = blockIdx.y;
  int e = blockIdx.x * 256 + threadIdx.x;
  const float* p = enc + (size_t)b * NL * NE + e;
  short* q = encbf + (size_t)b * NL * NE + e;
  float s = 0.f;
  for (int l = 0; l < NL; ++l) {
    float v = p[(size_t)l * NE];
    s += v;
    if (BF) q[(size_t)l * NE] = f2bf(v);
  }
  mean_enc[(size_t)b * NE + e] = s * (1.f / NL);
}

__global__ void k_xemb(const int* __restrict__ caps, const float* __restrict__ emb,
                       short* __restrict__ xemb) {
  int i = blockIdx.x * 256 + threadIdx.x;
  int m = i & (NM - 1), b = (i >> 9) & (NB - 1), t = i >> 15;
  xemb[i] = f2bf(emb[(size_t)caps[b * NT + t] * NM + m]);
}

// h0/c0 partials: 16-way K-split. grid (256, 16)
__global__ void k_init0(const float* __restrict__ mean_enc, const float* __restrict__ W_h0,
                        const float* __restrict__ W_c0, float* __restrict__ PP) {
  int idx = blockIdx.x * 256 + threadIdx.x;  // b*1024 + half*512 + j
  int ks = blockIdx.y;
  int b = idx >> 10, jh = idx & 1023, half = jh >> 9, j = jh & 511;
  const float* W = half ? W_c0 : W_h0;
  const float* mp = mean_enc + (size_t)b * NE + ks * 128;
  const float* Wp = W + (size_t)(ks * 128) * ND + j;
  float acc = 0.f;
#pragma unroll 4
  for (int k = 0; k < 128; ++k) acc = fmaf(mp[k], Wp[(size_t)k * ND], acc);
  PP[(size_t)ks * 65536 + idx] = acc;
}

__global__ void k_init1(const float* __restrict__ PP, const float* __restrict__ b_h0,
                        const float* __restrict__ b_c0, float* __restrict__ c0,
                        short* __restrict__ hb0) {
  int idx = blockIdx.x * 256 + threadIdx.x;  // b*512 + j
  int b = idx >> 9, j = idx & 511;
  float ah = b_h0[j], ac = b_c0[j];
  for (int s = 0; s < 16; ++s) {
    const float* p = PP + (size_t)s * 65536 + b * 1024;
    ah += p[j]; ac += p[512 + j];
  }
  c0[idx] = tanhf(ac);
  hb0[idx] = f2bf(tanhf(ah));
}

// e_proj = enc @ W_enc + b_enc (bf16 out). 128x128 tile, 1D grid 392, XCD-chunked
template <bool BF>
__global__ __launch_bounds__(256) void k_eproj(const float* __restrict__ enc,
                                               const short* __restrict__ encbf,
                                               const short* __restrict__ We_t,
                                               const float* __restrict__ b_enc,
                                               short* __restrict__ e_proj) {
  constexpr int FM = 4, FN = 4;  // 128 x 128
  __shared__ short ldsA[128 * 64], ldsB[128 * 64];
  // logical id: contiguous per XCD (p%8 = XCD under round-robin dispatch)
  int p = blockIdx.x;
  int l = (p & 7) * 49 + (p >> 3);       // 392 = 8*49
  int bn = (l & 3) * 128, bm = (l >> 2) * 128;
  int tid = threadIdx.x, lane = tid & 63, wave = tid >> 6, wr = wave >> 1, wc = wave & 1;
  f32x4 acc[FM][FN];
#pragma unroll
  for (int m = 0; m < FM; ++m)
#pragma unroll
    for (int n = 0; n < FN; ++n) acc[m][n] = (f32x4){0.f, 0.f, 0.f, 0.f};
  for (int k0 = 0; k0 < NE; k0 += 64) {
    __syncthreads();
    if (BF) stage_direct<128>(encbf + (size_t)bm * NE + k0, NE, 127, ldsA, tid);
    else    stage_f32cvt<128>(enc + (size_t)bm * NE + k0, NE, ldsA, tid);
    stage_direct<128>(We_t + (size_t)bn * NE + k0, NE, 127, ldsB, tid);
    __syncthreads();
    mma_tiles<FM, FN>(ldsA, ldsB, wr, wc, lane, acc);
  }
#pragma unroll
  for (int m = 0; m < FM; ++m)
#pragma unroll
    for (int n = 0; n < FN; ++n) {
      int col = bn + wc * FN * 16 + n * 16 + (lane & 15);
      float bias = b_enc[col];
#pragma unroll
      for (int r = 0; r < 4; ++r) {
        int row = bm + wr * FM * 16 + m * 16 + (lane >> 4) * 4 + r;
        e_proj[(size_t)row * NA + col] = f2bf(acc[m][n][r] + bias);
      }
    }
}

// fused h-GEMM: h_bf [64,512] @ Wall_t^T -> d | gate | preds(t). 64x64 tile
__global__ __launch_bounds__(256) void k_hgemm(const short* __restrict__ h_bf,
                                               const short* __restrict__ Wall_t,
                                               const float* __restrict__ b_dec,
                                               const float* __restrict__ b_beta,
                                               const float* __restrict__ b_fc,
                                               const int* __restrict__ clen,
                                               float* __restrict__ d_buf,
                                               float* __restrict__ gatebuf,
                                               float* __restrict__ preds, int t) {
  constexpr int FM = 2, FN = 2;  // 64 x 64, 4 waves
  __shared__ short ldsA[64 * 64], ldsB[64 * 64];
  int bn = blockIdx.x * 64;
  int tid = threadIdx.x, lane = tid & 63, wave = tid >> 6, wr = wave >> 1, wc = wave & 1;
  int rowClampB = NALL - 1 - bn; if (rowClampB > 63) rowClampB = 63;
  f32x4 acc[FM][FN];
#pragma unroll
  for (int m = 0; m < FM; ++m)
#pragma unroll
    for (int n = 0; n < FN; ++n) acc[m][n] = (f32x4){0.f, 0.f, 0.f, 0.f};
  for (int k0 = 0; k0 < ND; k0 += 64) {
    __syncthreads();
    stage_direct<64>(h_bf + k0, ND, 63, ldsA, tid);
    stage_direct<64>(Wall_t + (size_t)bn * ND + k0, ND, rowClampB, ldsB, tid);
    __syncthreads();
    mma_tiles<FM, FN>(ldsA, ldsB, wr, wc, lane, acc);
  }
#pragma unroll
  for (int m = 0; m < FM; ++m)
#pragma unroll
    for (int r = 0; r < 4; ++r) {
      int row = wr * FM * 16 + m * 16 + (lane >> 4) * 4 + r;  // batch
      float mf = ((clen[row] - 1) > t) ? 1.f : 0.f;
#pragma unroll
      for (int n = 0; n < FN; ++n) {
        int col = bn + wc * FN * 16 + n * 16 + (lane & 15);
        float a = acc[m][n][r];
        if (bn < OFF_GATE) {
          d_buf[(size_t)row * NA + col] = a + b_dec[col];
        } else if (bn < OFF_PRED) {
          int e = col - OFF_GATE;
          gatebuf[(size_t)row * NE + e] = sigmoidf_(a + b_beta[e]);
        } else {
          int v = col - OFF_PRED;
          if (v < NV) preds[((size_t)row * NML + t) * NV + v] = mf * (a + b_fc[v]);
        }
      }
    }
}

// ---------- per-step kernels ----------

__global__ __launch_bounds__(256) void k_energy(const short* __restrict__ e_proj,
                                                const float* __restrict__ d_buf,
                                                const float* __restrict__ w_att,
                                                const float* __restrict__ b_att,
                                                float* __restrict__ energy) {
  int tid = threadIdx.x, wave = tid >> 6, lane = tid & 63;
  int row = blockIdx.x * 4 + wave;  // b*196 + l
  int b = row / NL;
  short8v ev = *(const short8v*)(e_proj + (size_t)row * NA + lane * 8);
  const float* dp = d_buf + (size_t)b * NA + lane * 8;
  float4 d0 = *(const float4*)dp, d1 = *(const float4*)(dp + 4);
  const float* wp = w_att + lane * 8;
  float4 w0 = *(const float4*)wp, w1 = *(const float4*)(wp + 4);
  float dd[8] = {d0.x, d0.y, d0.z, d0.w, d1.x, d1.y, d1.z, d1.w};
  float ww[8] = {w0.x, w0.y, w0.z, w0.w, w1.x, w1.y, w1.z, w1.w};
  float acc = 0.f;
#pragma unroll
  for (int i = 0; i < 8; ++i) {
    float v = bf2f(ev[i]) + dd[i];
    acc = fmaf(fmaxf(v, 0.f), ww[i], acc);
  }
#pragma unroll
  for (int off = 32; off; off >>= 1) acc += __shfl_down(acc, off);
  if (lane == 0) energy[row] = acc + b_att[0];
}

// softmax (per-block recompute) + ctx + gate -> gctx bf16. grid (4, 64)
template <bool BF>
__global__ __launch_bounds__(256) void k_ctx(const short* __restrict__ encbf,
                                             const float* __restrict__ encf,
                                             const float* __restrict__ energy,
                                             const float* __restrict__ gatebuf,
                                             const int* __restrict__ clen,
                                             short* __restrict__ gctx,
                                             float* __restrict__ alphas_out, int t) {
  int b = blockIdx.y, e0 = blockIdx.x * 512, tid = threadIdx.x;
  __shared__ float al[NL];
  __shared__ float red[8];
  int wave = tid >> 6, lane = tid & 63;
  float v = (tid < NL) ? energy[b * NL + tid] : -INFINITY;
  float mx = v;
#pragma unroll
  for (int off = 32; off; off >>= 1) mx = fmaxf(mx, __shfl_down(mx, off));
  if (lane == 0) red[wave] = mx;
  __syncthreads();
  if (tid == 0) red[0] = fmaxf(fmaxf(red[0], red[1]), fmaxf(red[2], red[3]));
  __syncthreads();
  mx = red[0];
  float ex = (tid < NL) ? expf(v - mx) : 0.f;
  float sm = ex;
#pragma unroll
  for (int off = 32; off; off >>= 1) sm += __shfl_down(sm, off);
  if (lane == 0) red[4 + wave] = sm;
  __syncthreads();
  if (tid == 0) red[0] = 1.f / (red[4] + red[5] + red[6] + red[7]);
  __syncthreads();
  float alv = ex * red[0];
  if (tid < NL) {
    al[tid] = alv;
    if (blockIdx.x == 0) {
      float mf = ((clen[b] - 1) > t) ? 1.f : 0.f;
      alphas_out[((size_t)b * NML + t) * NL + tid] = alv * mf;
    }
  }
  __syncthreads();
  float cx0 = 0.f, cx1 = 0.f;
  if (BF) {
    const unsigned* p = (const unsigned*)(encbf + (size_t)b * NL * NE + e0) + tid;
#pragma unroll 4
    for (int l = 0; l < NL; ++l) {
      unsigned u = p[(size_t)l * (NE / 2)];
      cx0 = fmaf(al[l], bf2f((short)(u & 0xffffu)), cx0);
      cx1 = fmaf(al[l], bf2f((short)(u >> 16)), cx1);
    }
  } else {
    const float* p = encf + (size_t)b * NL * NE + e0 + 2 * tid;
#pragma unroll 4
    for (int l = 0; l < NL; ++l) {
      float2 u = *(const float2*)(p + (size_t)l * NE);
      cx0 = fmaf(al[l], u.x, cx0);
      cx1 = fmaf(al[l], u.y, cx1);
    }
  }
  int e = e0 + 2 * tid;
  const float* gp = gatebuf + (size_t)b * NE + e;
  unsigned out = (unsigned)(unsigned short)f2bf(cx0 * gp[0]) |
                 ((unsigned)(unsigned short)f2bf(cx1 * gp[1]) << 16);
  *(unsigned*)(gctx + (size_t)b * NE + e) = out;
}

// gates GEMM [emb|gctx|h] @ Wihx_t^T (col-interleaved) -> P[ks][64][2048]. grid (32, 8)
__global__ __launch_bounds__(256) void k_gates(const short* __restrict__ xemb_t,
                                               const short* __restrict__ gctx,
                                               const short* __restrict__ h_prev,
                                               const short* __restrict__ Wihx_t,
                                               float* __restrict__ P) {
  constexpr int FM = 2, FN = 2;  // 64 x 64
  __shared__ short ldsA[64 * 64], ldsB[64 * 64];
  int bn = blockIdx.x * 64, ks = blockIdx.y;
  int tid = threadIdx.x, lane = tid & 63, wave = tid >> 6, wr = wave >> 1, wc = wave & 1;
  f32x4 acc[FM][FN];
#pragma unroll
  for (int m = 0; m < FM; ++m)
#pragma unroll
    for (int n = 0; n < FN; ++n) acc[m][n] = (f32x4){0.f, 0.f, 0.f, 0.f};
  int kend = (ks + 1) * KSL;
  for (int k0 = ks * KSL; k0 < kend; k0 += 64) {
    const short* asrc; int aldk;
    if (k0 < NM)           { asrc = xemb_t + k0;              aldk = NM; }
    else if (k0 < NM + NE) { asrc = gctx + (k0 - NM);         aldk = NE; }
    else                   { asrc = h_prev + (k0 - NM - NE);  aldk = ND; }
    __syncthreads();
    stage_direct<64>(asrc, aldk, 63, ldsA, tid);
    stage_direct<64>(Wihx_t + (size_t)bn * KXG + k0, KXG, 63, ldsB, tid);
    __syncthreads();
    mma_tiles<FM, FN>(ldsA, ldsB, wr, wc, lane, acc);
  }
#pragma unroll
  for (int m = 0; m < FM; ++m)
#pragma unroll
    for (int n = 0; n < FN; ++n) {
      int col = bn + wc * FN * 16 + n * 16 + (lane & 15);
#pragma unroll
      for (int r = 0; r < 4; ++r) {
        int row = wr * FM * 16 + m * 16 + (lane >> 4) * 4 + r;
        P[((size_t)ks * NB + row) * NG + col] = acc[m][n][r];
      }
    }
}

// reduce K-split partials (col-interleaved: col = j*4+g -> float4 = {i,f,g,o}),
// LSTM pointwise, write c_next / h_next(bf16)
__global__ void k_lstm(const float* __restrict__ P, const float* __restrict__ b_ih,
                       const float* __restrict__ b_hh, const float* __restrict__ c_prev,
                       float* __restrict__ c_next, short* __restrict__ h_next) {
  int idx = blockIdx.x * 256 + threadIdx.x;  // b*512 + j
  int b = idx >> 9, j = idx & (ND - 1);
  float gi = b_ih[j] + b_hh[j];
  float gf = b_ih[j + ND] + b_hh[j + ND];
  float gg = b_ih[j + 2 * ND] + b_hh[j + 2 * ND];
  float go = b_ih[j + 3 * ND] + b_hh[j + 3 * ND];
#pragma unroll
  for (int s = 0; s < KSPL; ++s) {
    float4 v = *(const float4*)&P[((size_t)s * NB + b) * NG + j * 4];
    gi += v.x; gf += v.y; gg += v.z; go += v.w;
  }
  float cn = sigmoidf_(gf) * c_prev[idx] + sigmoidf_(gi) * tanhf(gg);
  float hn = sigmoidf_(go) * tanhf(cn);
  c_next[idx] = cn;
  h_next[idx] = f2bf(hn);
}

}  // namespace

extern "C" void kernel_launch(void* const* d_in, const int* in_sizes, int n_in,
                              void* d_out, int out_size, void* d_ws, size_t ws_size,
                              hipStream_t stream) {
  (void)in_sizes; (void)n_in; (void)out_size;
  const float* enc    = (const float*)d_in[0];
  const int*   caps   = (const int*)d_in[1];
  const int*   clen   = (const int*)d_in[2];
  const float* W_enc  = (const float*)d_in[3];
  const float* b_enc  = (const float*)d_in[4];
  const float* W_dec  = (const float*)d_in[5];
  const float* b_dec  = (const float*)d_in[6];
  const float* w_att  = (const float*)d_in[7];
  const float* b_att  = (const float*)d_in[8];
  const float* emb    = (const float*)d_in[9];
  const float* W_ih   = (const float*)d_in[10];
  const float* b_ih   = (const float*)d_in[11];
  const float* W_hh   = (const float*)d_in[12];
  const float* b_hh   = (const float*)d_in[13];
  const float* W_h0   = (const float*)d_in[14];
  const float* b_h0   = (const float*)d_in[15];
  const float* W_c0   = (const float*)d_in[16];
  const float* b_c0   = (const float*)d_in[17];
  const float* W_beta = (const float*)d_in[18];
  const float* b_beta = (const float*)d_in[19];
  const float* W_fc   = (const float*)d_in[20];
  const float* b_fc   = (const float*)d_in[21];

  float* ws     = (float*)d_ws;
  float* preds  = (float*)d_out;                   // [B][ML][V]
  float* alphas = preds + (size_t)NB * NML * NV;   // [B][ML][L]

  float* mean_enc = ws + WS_MEAN;
  float* cbuf[2]  = {ws + WS_C0, ws + WS_C1};
  float* d_buf    = ws + WS_D;
  float* gatebuf  = ws + WS_GATE;
  float* energy   = ws + WS_EN;
  float* PP       = ws + WS_PP;
  short* shb      = (short*)(ws + WS_SHB);
  short* hbuf[2]  = {shb + SH_HB0, shb + SH_HB1};
  short* xemb     = shb + SH_XEMB;
  short* gctx     = shb + SH_GCTX;
  short* e_proj   = shb + SH_EPROJ;
  short* We_t     = shb + SH_WET;
  short* Wihx_t   = shb + SH_WIHX;
  short* Wall_t   = shb + SH_WALL;
  short* encbf    = shb + SH_ENCBF;
  const bool use_bf = ws_size >= BYTES_ENC;

  // one-time weight transposes (dst[n][k] bf16)
  k_tcvt<false><<<dim3(NA / 32, NE / 32), dim3(32, 8), 0, stream>>>(W_enc, NE, NA, We_t, NE, 0);
  k_tcvt<true><<<dim3(NG / 32, (NM + NE) / 32), dim3(32, 8), 0, stream>>>(
      W_ih, NM + NE, NG, Wihx_t, KXG, 0);
  k_tcvt<true><<<dim3(NG / 32, ND / 32), dim3(32, 8), 0, stream>>>(
      W_hh, ND, NG, Wihx_t, KXG, NM + NE);
  k_tcvt<false><<<dim3(NA / 32, ND / 32), dim3(32, 8), 0, stream>>>(W_dec, ND, NA, Wall_t, ND, 0);
  k_tcvt<false><<<dim3(NE / 32, ND / 32), dim3(32, 8), 0, stream>>>(
      W_beta, ND, NE, Wall_t + (size_t)OFF_GATE * ND, ND, 0);
  k_tcvt<false><<<dim3((NV + 31) / 32, ND / 32), dim3(32, 8), 0, stream>>>(
      W_fc, ND, NV, Wall_t + (size_t)OFF_PRED * ND, ND, 0);
  if (use_bf)
    k_prep<true><<<dim3(NE / 256, NB), 256, 0, stream>>>(enc, encbf, mean_enc);
  else
    k_prep<false><<<dim3(NE / 256, NB), 256, 0, stream>>>(enc, encbf, mean_enc);
  k_xemb<<<(NML * NB * NM) / 256, 256, 0, stream>>>(caps, emb, xemb);

  k_init0<<<dim3(256, 16), 256, 0, stream>>>(mean_enc, W_h0, W_c0, PP);
  k_init1<<<(NB * ND) / 256, 256, 0, stream>>>(PP, b_h0, b_c0, cbuf[0], hbuf[0]);
  if (use_bf)
    k_eproj<true><<<392, 256, 0, stream>>>(enc, encbf, We_t, b_enc, e_proj);
  else
    k_eproj<false><<<392, 256, 0, stream>>>(enc, encbf, We_t, b_enc, e_proj);
  // h0-dependent d + gate only (first 40 column-tiles)
  k_hgemm<<<OFF_PRED / 64, 256, 0, stream>>>(hbuf[0], Wall_t, b_dec, b_beta, b_fc, clen,
                                             d_buf, gatebuf, preds, 0);

  for (int t = 0; t < NML; ++t) {
    short* h_prev = hbuf[t & 1];
    short* h_next = hbuf[1 - (t & 1)];
    float* c_prev = cbuf[t & 1];
    float* c_next = cbuf[1 - (t & 1)];
    k_energy<<<(NB * NL) / 4, 256, 0, stream>>>(e_proj, d_buf, w_att, b_att, energy);
    if (use_bf)
      k_ctx<true><<<dim3(NE / 512, NB), 256, 0, stream>>>(encbf, enc, energy, gatebuf,
                                                          clen, gctx, alphas, t);
    else
      k_ctx<false><<<dim3(NE / 512, NB), 256, 0, stream>>>(encbf, enc, energy, gatebuf,
                                                           clen, gctx, alphas, t);
    k_gates<<<dim3(NG / 64, KSPL), 256, 0, stream>>>(xemb + (size_t)t * NB * NM, gctx,
                                                     h_prev, Wihx_t, PP);
    k_lstm<<<(NB * ND) / 256, 256, 0, stream>>>(PP, b_ih, b_hh, c_prev, c_next, h_next);
    // preds(t) + d/gate for step t+1
    k_hgemm<<<(NALL + 63) / 64, 256, 0, stream>>>(h_next, Wall_t, b_dec, b_beta, b_fc,
                                                  clen, d_buf, gatebuf, preds, t);
  }
}